// Round 2
// baseline (1027.003 us; speedup 1.0000x reference)
//
#include <hip/hip_runtime.h>
#include <math.h>

#define BLOCK 256

__global__ __launch_bounds__(BLOCK)
void lsl_kernel(const float* __restrict__ probs,
                const int* __restrict__ target,
                float* __restrict__ result,
                int N, int V,
                double conf, double sm,
                double base_ne, double base_eq)
{
    const int row = blockIdx.x;
    if (row >= N) return;
    const int tid = threadIdx.x;
    const float* rp = probs + (size_t)row * (size_t)V;

    const float eps = 1e-12f;
    float acc = 0.0f;

    // Peel to 16 B alignment: V = 50257 is odd, so row base alignment rotates mod 16 B.
    int mis = ((int)((uintptr_t)rp >> 2)) & 3;   // leading floats before next 16B boundary
    int pre = (4 - mis) & 3;
    if (pre > V) pre = V;
    if (tid < pre) acc += __logf(rp[tid] + eps);

    const int rem  = V - pre;
    const int nvec = rem >> 2;
    const float4* vp = (const float4*)(rp + pre);
    for (int i = tid; i < nvec; i += BLOCK) {
        float4 v = vp[i];
        acc += __logf(v.x + eps);
        acc += __logf(v.y + eps);
        acc += __logf(v.z + eps);
        acc += __logf(v.w + eps);
    }
    const int tail0 = pre + (nvec << 2);
    for (int i = tail0 + tid; i < V; i += BLOCK)
        acc += __logf(rp[i] + eps);

    // Wave-64 butterfly reduce, then cross-wave via LDS.
    #pragma unroll
    for (int off = 32; off > 0; off >>= 1)
        acc += __shfl_down(acc, off, 64);
    __shared__ float wsum[BLOCK / 64];
    if ((tid & 63) == 0) wsum[tid >> 6] = acc;
    __syncthreads();

    if (tid == 0) {
        float S = 0.0f;
        #pragma unroll
        for (int w = 0; w < BLOCK / 64; ++w) S += wsum[w];

        const int t = target[row];
        if (t != -100) {                         // IGNORE_INDEX
            const int ign_col = V - 100;         // JAX .at[-100] wraps to V-100
            const double lp_t = (double)__logf(rp[t] + eps);
            double kl;
            if (t == ign_col) {
                // target coincides with the zeroed column: no zero entry in the row
                kl = base_eq - conf * lp_t - sm * ((double)S - lp_t);
            } else {
                const double lp_i = (double)__logf(rp[ign_col] + eps);
                kl = base_ne - conf * lp_t - sm * ((double)S - lp_t - lp_i);
            }
            atomicAdd(result, (float)kl);
        }
    }
}

extern "C" void kernel_launch(void* const* d_in, const int* in_sizes, int n_in,
                              void* d_out, int out_size, void* d_ws, size_t ws_size,
                              hipStream_t stream)
{
    const float* probs  = (const float*)d_in[0];
    const int*   target = (const int*)d_in[1];
    float*       result = (float*)d_out;

    const int N = in_sizes[1];                       // 4096 rows
    const int V = (int)((long long)in_sizes[0] / N); // 50257 vocab

    const double conf = 1.0 - 0.1;                   // 1 - LABEL_SMOOTHING
    const double sm   = 0.1 / (double)(V - 1);       // smoothing value
    const double cc   = conf * log(conf);
    const double sl   = sm * log(sm);
    const double base_ne = cc + (double)(V - 2) * sl; // t != ign_col: V-2 smoothing cells
    const double base_eq = cc + (double)(V - 1) * sl; // t == ign_col: V-1 smoothing cells

    hipMemsetAsync(d_out, 0, (size_t)out_size * sizeof(float), stream);
    lsl_kernel<<<N, BLOCK, 0, stream>>>(probs, target, result, N, V,
                                        conf, sm, base_ne, base_eq);
}